// Round 12
// baseline (69.289 us; speedup 1.0000x reference)
//
#include <hip/hip_runtime.h>

#define B_  4
#define NQ_ 256
#define NK_ 512
#define H_  256
#define PADK 516   // half8s per kt row (512 + pad): row stride 8256B, not 8KB

typedef _Float16 half8 __attribute__((ext_vector_type(8)));
typedef _Float16 half4_t __attribute__((ext_vector_type(4)));
typedef float    f4     __attribute__((ext_vector_type(4)));  // clang vec: ok for nontemporal

// tanh via exp2; clamp to +-0.99951172 (largest fp16 < 1) so after fp16
// rounding |ta| <= 0.99951172 and 1 + ta*tb >= 4.88e-4 > 0 always.
#define TWO_LOG2E 2.8853900817779268f
__device__ __forceinline__ float tanh_fast(float x) {
    float t = __builtin_amdgcn_exp2f(x * TWO_LOG2E);
    float r = __builtin_amdgcn_rcpf(t + 1.0f);
    float y = fmaf(-2.0f, r, 1.0f);
    return fminf(fmaxf(y, -0.99951172f), 0.99951172f);
}

// Both GEMMs in one launch, 64x64 tiles, 256 threads, 16 outputs/thread,
// register-double-buffered staging. Epilogue stores are NONTEMPORAL so the
// results don't sit dirty in this XCD's L2 (attn blocks on other XCDs would
// pay a dirty-remote-line writeback on every first read).
// blocks [0,128):  kt[b][o][k] -> ktH[b][o>>3][k][o&7] = fp16(tanh(kt))
// blocks [128,192): qt[b][q][o] -> tbT[b][q][o] = f32 tanh(qt)
__global__ __launch_bounds__(256)
void gemm_fused(const float* __restrict__ xq, const float* __restrict__ xk,
                const float* __restrict__ w1, const float* __restrict__ w2,
                _Float16* __restrict__ ktH,   // [B][32][PADK][8] halves
                float* __restrict__ tbT)      // [B][NQ][H]
{
    constexpr int BK = 32;
    const float* A; const float* Bm;
    int m0, n0, bz; bool iskt;
    {
        int id = blockIdx.x;
        if (id < 128) {                      // kt: M=H(o), N=NK(k)
            iskt = true;
            bz = id >> 5; int t = id & 31;
            m0 = (t >> 3) * 64; n0 = (t & 7) * 64;
            A = w1; Bm = xk + (long)bz * NK_ * H_;
        } else {                             // qt: M=NQ(q), N=H(o)
            iskt = false;
            id -= 128;
            bz = id >> 4; int t = id & 15;
            m0 = (t >> 2) * 64; n0 = (t & 3) * 64;
            A = xq + (long)bz * NQ_ * H_; Bm = w2;
        }
    }
    const int lda = H_, ldb = H_;

    __shared__ float As[BK][68];
    __shared__ float Bs[BK][68];

    const int tid  = threadIdx.x;
    const int lrow = tid >> 2;          // 0..63
    const int lk   = (tid & 3) * 8;     // {0,8,16,24}
    const int tm   = (tid >> 4) * 4;
    const int tn   = (tid & 15) * 4;

    float acc[4][4] = {};

    float4 a0_r = *(const float4*)&A [(long)(m0 + lrow) * lda + lk];
    float4 a1_r = *(const float4*)&A [(long)(m0 + lrow) * lda + lk + 4];
    float4 b0_r = *(const float4*)&Bm[(long)(n0 + lrow) * ldb + lk];
    float4 b1_r = *(const float4*)&Bm[(long)(n0 + lrow) * ldb + lk + 4];
    float4 a0_n = a0_r, a1_n = a1_r, b0_n = b0_r, b1_n = b1_r;

    for (int kt = 0; kt < H_; kt += BK) {
        __syncthreads();
        As[lk+0][lrow]=a0_r.x; As[lk+1][lrow]=a0_r.y; As[lk+2][lrow]=a0_r.z; As[lk+3][lrow]=a0_r.w;
        As[lk+4][lrow]=a1_r.x; As[lk+5][lrow]=a1_r.y; As[lk+6][lrow]=a1_r.z; As[lk+7][lrow]=a1_r.w;
        Bs[lk+0][lrow]=b0_r.x; Bs[lk+1][lrow]=b0_r.y; Bs[lk+2][lrow]=b0_r.z; Bs[lk+3][lrow]=b0_r.w;
        Bs[lk+4][lrow]=b1_r.x; Bs[lk+5][lrow]=b1_r.y; Bs[lk+6][lrow]=b1_r.z; Bs[lk+7][lrow]=b1_r.w;
        if (kt + BK < H_) {
            a0_n = *(const float4*)&A [(long)(m0 + lrow) * lda + kt + BK + lk];
            a1_n = *(const float4*)&A [(long)(m0 + lrow) * lda + kt + BK + lk + 4];
            b0_n = *(const float4*)&Bm[(long)(n0 + lrow) * ldb + kt + BK + lk];
            b1_n = *(const float4*)&Bm[(long)(n0 + lrow) * ldb + kt + BK + lk + 4];
        }
        __syncthreads();
        #pragma unroll
        for (int kk = 0; kk < BK; ++kk) {
            float4 av = *(const float4*)&As[kk][tm];
            float4 bv = *(const float4*)&Bs[kk][tn];
            float am[4] = {av.x, av.y, av.z, av.w};
            float bn[4] = {bv.x, bv.y, bv.z, bv.w};
            #pragma unroll
            for (int i = 0; i < 4; ++i)
                #pragma unroll
                for (int j = 0; j < 4; ++j)
                    acc[i][j] = fmaf(am[i], bn[j], acc[i][j]);
        }
        a0_r = a0_n; a1_r = a1_n; b0_r = b0_n; b1_r = b1_n;
    }

    if (iskt) {
        // o rows m0+tm..+3 are inside 8-group g8=(m0+tm)>>3 at offset tm&7 in {0,4}
        const long gbase = ((long)bz * 32 + ((m0 + tm) >> 3)) * PADK * 8 + (tm & 7);
        #pragma unroll
        for (int j = 0; j < 4; ++j) {
            half4_t h4 = { (_Float16)tanh_fast(acc[0][j]), (_Float16)tanh_fast(acc[1][j]),
                           (_Float16)tanh_fast(acc[2][j]), (_Float16)tanh_fast(acc[3][j]) };
            __builtin_nontemporal_store(h4, (half4_t*)&ktH[gbase + (long)(n0 + tn + j) * 8]);
        }
    } else {
        #pragma unroll
        for (int i = 0; i < 4; ++i) {
            f4 t4 = { tanh_fast(acc[i][0]), tanh_fast(acc[i][1]),
                      tanh_fast(acc[i][2]), tanh_fast(acc[i][3]) };
            __builtin_nontemporal_store(t4,
                (f4*)&tbT[((long)bz * NQ_ + m0 + tm + i) * H_ + n0 + tn]);
        }
    }
}

// One block per (b, 4 q-rows), 512 threads = one per k. kv is fp16 half8.
// kv prefetch deepened to 8 rows in flight (3-buffer named rotation): if the
// binding constraint is first-read latency on freshly-written remote lines,
// doubling outstanding loads halves the exposure.
__global__ __launch_bounds__(512, 1)
void attn_main(const half8* __restrict__ ktH,  // [B][32][PADK]
               const float4* __restrict__ tbT, // [B][NQ][H/4]
               const float4* __restrict__ v4p, // [H/4]
               float* __restrict__ out)        // [B][NQ][NK]
{
    const int k = threadIdx.x, b = blockIdx.y, q0 = blockIdx.x * 4;

    __shared__ float4 sT[4][64];
    __shared__ float4 sV[64];
    if (k < 256) {
        const int q = k >> 6, idx = k & 63;
        sT[q][idx] = tbT[((long)b * NQ_ + q0 + q) * 64 + idx];
    } else if (k < 320) {
        sV[k & 63] = v4p[k & 63];
    }
    __syncthreads();

    const half8* kp = ktH + (long)b * 32 * PADK + k;

    float ac0 = 0.f, ac1 = 0.f, ac2 = 0.f, ac3 = 0.f;

    // 8-deep prefetch: A = current group, B = next group, C = landing buffer
    half8 ka0 = kp[0 * PADK], ka1 = kp[1 * PADK], ka2 = kp[2 * PADK], ka3 = kp[3 * PADK];
    half8 kb0 = kp[4 * PADK], kb1 = kp[5 * PADK], kb2 = kp[6 * PADK], kb3 = kp[7 * PADK];
    half8 kc0 = ka0, kc1 = ka1, kc2 = ka2, kc3 = ka3;

#define QSTEP(ACC, A0, A1, A2, A3, TB, VV)                                    \
    {                                                                         \
        float d0 = fmaf(A0, TB.x, 1.f), d1 = fmaf(A1, TB.y, 1.f);             \
        float d2 = fmaf(A2, TB.z, 1.f), d3 = fmaf(A3, TB.w, 1.f);             \
        float p0 = VV.x * (A0 + TB.x), p1 = VV.y * (A1 + TB.y);               \
        float p2 = VV.z * (A2 + TB.z), p3 = VV.w * (A3 + TB.w);               \
        float D01 = d0 * d1, D23 = d2 * d3;                                   \
        float N01 = fmaf(p0, d1, p1 * d0);                                    \
        float N23 = fmaf(p2, d3, p3 * d2);                                    \
        ACC = fmaf(fmaf(N01, D23, N23 * D01),                                 \
                   __builtin_amdgcn_rcpf(D01 * D23), ACC);                    \
    }
#define PROC8(KV, G)                                                          \
    {                                                                         \
        float f0 = (float)KV[0], f1 = (float)KV[1], f2 = (float)KV[2],        \
              f3 = (float)KV[3], f4 = (float)KV[4], f5 = (float)KV[5],        \
              f6 = (float)KV[6], f7 = (float)KV[7];                           \
        float4 va = sV[2 * (G)], vb = sV[2 * (G) + 1];                        \
        float4 t0a = sT[0][2 * (G)], t0b = sT[0][2 * (G) + 1];                \
        QSTEP(ac0, f0, f1, f2, f3, t0a, va)                                   \
        QSTEP(ac0, f4, f5, f6, f7, t0b, vb)                                   \
        float4 t1a = sT[1][2 * (G)], t1b = sT[1][2 * (G) + 1];                \
        QSTEP(ac1, f0, f1, f2, f3, t1a, va)                                   \
        QSTEP(ac1, f4, f5, f6, f7, t1b, vb)                                   \
        float4 t2a = sT[2][2 * (G)], t2b = sT[2][2 * (G) + 1];                \
        QSTEP(ac2, f0, f1, f2, f3, t2a, va)                                   \
        QSTEP(ac2, f4, f5, f6, f7, t2b, vb)                                   \
        float4 t3a = sT[3][2 * (G)], t3b = sT[3][2 * (G) + 1];                \
        QSTEP(ac3, f0, f1, f2, f3, t3a, va)                                   \
        QSTEP(ac3, f4, f5, f6, f7, t3b, vb)                                   \
    }

    for (int g = 0; g < 32; g += 4) {
        if (g + 8 < 32) {          // land rows g+8..g+11 in C
            kc0 = kp[(long)(g +  8) * PADK];
            kc1 = kp[(long)(g +  9) * PADK];
            kc2 = kp[(long)(g + 10) * PADK];
            kc3 = kp[(long)(g + 11) * PADK];
        }
        PROC8(ka0, g + 0)
        PROC8(ka1, g + 1)
        PROC8(ka2, g + 2)
        PROC8(ka3, g + 3)
        ka0 = kb0; ka1 = kb1; ka2 = kb2; ka3 = kb3;
        kb0 = kc0; kb1 = kc1; kb2 = kc2; kb3 = kc3;
    }
#undef PROC8
#undef QSTEP

    // ---- log-softmax over k, no max pass (|val| <= sum|v| ~ 8, fp32-safe) ----
    __shared__ float red[8][4];
    const int lane = k & 63, wv = k >> 6;
    float acc[4] = {ac0, ac1, ac2, ac3};

    #pragma unroll
    for (int j = 0; j < 4; ++j) {
        float e = __builtin_amdgcn_exp2f(acc[j] * 1.4426950408889634f);
        #pragma unroll
        for (int o = 32; o; o >>= 1) e += __shfl_xor(e, o, 64);
        if (lane == 0) red[wv][j] = e;
    }
    __syncthreads();
    #pragma unroll
    for (int j = 0; j < 4; ++j) {
        float s = 0.f;
        #pragma unroll
        for (int w = 0; w < 8; ++w) s += red[w][j];
        float l = __builtin_amdgcn_logf(s) * 0.6931471805599453f;  // ln(s)
        out[((long)b * NQ_ + q0 + j) * NK_ + k] = acc[j] - l;
    }
}

extern "C" void kernel_launch(void* const* d_in, const int* in_sizes, int n_in,
                              void* d_out, int out_size, void* d_ws, size_t ws_size,
                              hipStream_t stream)
{
    const float* xq = (const float*)d_in[0];  // (4,256,256)
    const float* xk = (const float*)d_in[1];  // (4,512,256)
    const float* w1 = (const float*)d_in[2];  // (256,256) out,in
    const float* w2 = (const float*)d_in[3];  // (256,256)
    const float* v  = (const float*)d_in[4];  // (1,256)
    float* out = (float*)d_out;

    _Float16* ktH = (_Float16*)d_ws;                      // [4][32][516][8] fp16 ~1.06MB
    float* tbT = (float*)((char*)d_ws + (size_t)B_ * 32 * PADK * 8 * 2);  // 1MB f32

    gemm_fused<<<dim3(192), 256, 0, stream>>>(xq, xk, w1, w2, ktH, tbT);
    // MEASUREMENT: attn launched twice (idempotent). With gemm ~= 12 us known,
    // attn = (dur_us - 12) / 2. Remove the duplicate next round.
    attn_main<<<dim3(NQ_ / 4, B_), 512, 0, stream>>>(
        (const half8*)ktH, (const float4*)tbT, (const float4*)v, out);
    attn_main<<<dim3(NQ_ / 4, B_), 512, 0, stream>>>(
        (const half8*)ktH, (const float4*)tbT, (const float4*)v, out);
}

// Round 13
// 38.239 us; speedup vs baseline: 1.8120x; 1.8120x over previous
//
#include <hip/hip_runtime.h>

#define B_  4
#define NQ_ 256
#define NK_ 512
#define H_  256
#define PADE 516   // float4s per E row (512 + 4 pad): stride 8256B, not 8KB

// 2*log2(e): exp2(x*TWO_LOG2E) = e^{2x}
#define TWO_LOG2E 2.8853900817779268f

// Both GEMMs in one launch, 64x64 tiles, 256 threads, 16 outputs/thread,
// register-double-buffered staging. Epilogues store EXP of the transforms:
//   blocks [0,128):  E[b][o>>2][k][o&3] = e^{2*kt[b][o][k]}   (padded rows)
//   blocks [128,192): F[b][q][o]        = e^{2*qt[b][q][o]}
// tanh(a+b) = 1 - 2/(1 + e^{2a}e^{2b}) is EXACT -- no clamp needed; d>=1.
__global__ __launch_bounds__(256)
void gemm_fused(const float* __restrict__ xq, const float* __restrict__ xk,
                const float* __restrict__ w1, const float* __restrict__ w2,
                float* __restrict__ Ebuf,    // [B][64][PADE*4] floats
                float* __restrict__ Fbuf)    // [B][NQ][H]
{
    constexpr int BK = 32;
    const float* A; const float* Bm;
    int m0, n0, bz; bool iskt;
    {
        int id = blockIdx.x;
        if (id < 128) {                      // kt: M=H(o), N=NK(k)
            iskt = true;
            bz = id >> 5; int t = id & 31;
            m0 = (t >> 3) * 64; n0 = (t & 7) * 64;
            A = w1; Bm = xk + (long)bz * NK_ * H_;
        } else {                             // qt: M=NQ(q), N=H(o)
            iskt = false;
            id -= 128;
            bz = id >> 4; int t = id & 15;
            m0 = (t >> 2) * 64; n0 = (t & 3) * 64;
            A = xq + (long)bz * NQ_ * H_; Bm = w2;
        }
    }
    const int lda = H_, ldb = H_;

    __shared__ float As[BK][68];
    __shared__ float Bs[BK][68];

    const int tid  = threadIdx.x;
    const int lrow = tid >> 2;          // 0..63
    const int lk   = (tid & 3) * 8;     // {0,8,16,24}
    const int tm   = (tid >> 4) * 4;
    const int tn   = (tid & 15) * 4;

    float acc[4][4] = {};

    float4 a0_r = *(const float4*)&A [(long)(m0 + lrow) * lda + lk];
    float4 a1_r = *(const float4*)&A [(long)(m0 + lrow) * lda + lk + 4];
    float4 b0_r = *(const float4*)&Bm[(long)(n0 + lrow) * ldb + lk];
    float4 b1_r = *(const float4*)&Bm[(long)(n0 + lrow) * ldb + lk + 4];
    float4 a0_n = a0_r, a1_n = a1_r, b0_n = b0_r, b1_n = b1_r;

    for (int kt = 0; kt < H_; kt += BK) {
        __syncthreads();
        As[lk+0][lrow]=a0_r.x; As[lk+1][lrow]=a0_r.y; As[lk+2][lrow]=a0_r.z; As[lk+3][lrow]=a0_r.w;
        As[lk+4][lrow]=a1_r.x; As[lk+5][lrow]=a1_r.y; As[lk+6][lrow]=a1_r.z; As[lk+7][lrow]=a1_r.w;
        Bs[lk+0][lrow]=b0_r.x; Bs[lk+1][lrow]=b0_r.y; Bs[lk+2][lrow]=b0_r.z; Bs[lk+3][lrow]=b0_r.w;
        Bs[lk+4][lrow]=b1_r.x; Bs[lk+5][lrow]=b1_r.y; Bs[lk+6][lrow]=b1_r.z; Bs[lk+7][lrow]=b1_r.w;
        if (kt + BK < H_) {
            a0_n = *(const float4*)&A [(long)(m0 + lrow) * lda + kt + BK + lk];
            a1_n = *(const float4*)&A [(long)(m0 + lrow) * lda + kt + BK + lk + 4];
            b0_n = *(const float4*)&Bm[(long)(n0 + lrow) * ldb + kt + BK + lk];
            b1_n = *(const float4*)&Bm[(long)(n0 + lrow) * ldb + kt + BK + lk + 4];
        }
        __syncthreads();
        #pragma unroll
        for (int kk = 0; kk < BK; ++kk) {
            float4 av = *(const float4*)&As[kk][tm];
            float4 bv = *(const float4*)&Bs[kk][tn];
            float am[4] = {av.x, av.y, av.z, av.w};
            float bn[4] = {bv.x, bv.y, bv.z, bv.w};
            #pragma unroll
            for (int i = 0; i < 4; ++i)
                #pragma unroll
                for (int j = 0; j < 4; ++j)
                    acc[i][j] = fmaf(am[i], bn[j], acc[i][j]);
        }
        a0_r = a0_n; a1_r = a1_n; b0_r = b0_n; b1_r = b1_n;
    }

    if (iskt) {
        // rows o = m0+tm..+3 consecutive -> one float4 per output column k
        float4* cb = (float4*)Ebuf + ((long)bz * 64 + ((m0 + tm) >> 2)) * PADE;
        #pragma unroll
        for (int j = 0; j < 4; ++j) {
            float4 e4 = { __builtin_amdgcn_exp2f(acc[0][j] * TWO_LOG2E),
                          __builtin_amdgcn_exp2f(acc[1][j] * TWO_LOG2E),
                          __builtin_amdgcn_exp2f(acc[2][j] * TWO_LOG2E),
                          __builtin_amdgcn_exp2f(acc[3][j] * TWO_LOG2E) };
            cb[n0 + tn + j] = e4;
        }
    } else {
        #pragma unroll
        for (int i = 0; i < 4; ++i) {
            float4 f4v = { __builtin_amdgcn_exp2f(acc[i][0] * TWO_LOG2E),
                           __builtin_amdgcn_exp2f(acc[i][1] * TWO_LOG2E),
                           __builtin_amdgcn_exp2f(acc[i][2] * TWO_LOG2E),
                           __builtin_amdgcn_exp2f(acc[i][3] * TWO_LOG2E) };
            *(float4*)&Fbuf[((long)bz * NQ_ + m0 + tm + i) * H_ + n0 + tn] = f4v;
        }
    }
}

// One block per (b, 2 q-rows), 512 threads = one per k.
// prod[q,k] = -2 * sum_h v[h] / (1 + E[h,k]*F[q,h])   (Sum v cancels in LSM)
// F and v are WAVE-UNIFORM -> s_load into SGPRs; VALU reads SGPR operands
// directly. Zero LDS / zero VMEM on the operand side: removes the shared
// per-CU broadcast-pipe load that was the invariant ~26us across rounds 3-12.
// E is the only vector stream: 1 float4 per 4h, 8-deep register prefetch.
__global__ __launch_bounds__(512, 2)
void attn_main(const float4* __restrict__ E4,   // [B][64][PADE]
               const float* __restrict__ Fbuf,  // [B][NQ][H]
               const float* __restrict__ v,     // [H]
               float* __restrict__ out)         // [B][NQ][NK]
{
    const int k = threadIdx.x, b = blockIdx.y, q0 = blockIdx.x * 2;

    const float4* kp  = E4 + (long)b * 64 * PADE + k;
    const float4* F0p = (const float4*)(Fbuf + ((long)b * NQ_ + q0) * H_);
    const float4* F1p = F0p + (H_ / 4);
    const float4* v4p = (const float4*)v;

    float T0 = 0.f, T1 = 0.f;

    // 8-deep E prefetch: A = current group, B = next, C = landing
    float4 ka0 = kp[0*PADE], ka1 = kp[1*PADE], ka2 = kp[2*PADE], ka3 = kp[3*PADE];
    float4 kb0 = kp[4*PADE], kb1 = kp[5*PADE], kb2 = kp[6*PADE], kb3 = kp[7*PADE];
    float4 kc0 = ka0, kc1 = ka1, kc2 = ka2, kc3 = ka3;

#define PROC4(EV, HC)                                                         \
    {                                                                         \
        float4 f0 = F0p[HC];             /* uniform -> s_load_dwordx4 */      \
        float4 f1 = F1p[HC];                                                  \
        float4 vv = v4p[HC];                                                  \
        {   /* q0 */                                                          \
            float d0 = fmaf(EV.x, f0.x, 1.f), d1 = fmaf(EV.y, f0.y, 1.f);     \
            float d2 = fmaf(EV.z, f0.z, 1.f), d3 = fmaf(EV.w, f0.w, 1.f);     \
            float D01 = d0 * d1, D23 = d2 * d3;                               \
            float N01 = fmaf(vv.x, d1, vv.y * d0);                            \
            float N23 = fmaf(vv.z, d3, vv.w * d2);                            \
            float N   = fmaf(N01, D23, N23 * D01);                            \
            T0 = fmaf(N, __builtin_amdgcn_rcpf(D01 * D23), T0);               \
        }                                                                     \
        {   /* q1 */                                                          \
            float d0 = fmaf(EV.x, f1.x, 1.f), d1 = fmaf(EV.y, f1.y, 1.f);     \
            float d2 = fmaf(EV.z, f1.z, 1.f), d3 = fmaf(EV.w, f1.w, 1.f);     \
            float D01 = d0 * d1, D23 = d2 * d3;                               \
            float N01 = fmaf(vv.x, d1, vv.y * d0);                            \
            float N23 = fmaf(vv.z, d3, vv.w * d2);                            \
            float N   = fmaf(N01, D23, N23 * D01);                            \
            T1 = fmaf(N, __builtin_amdgcn_rcpf(D01 * D23), T1);               \
        }                                                                     \
    }

    for (int g = 0; g < 64; g += 4) {
        if (g + 8 < 64) {          // land rows g+8..g+11 in C
            kc0 = kp[(long)(g +  8) * PADE];
            kc1 = kp[(long)(g +  9) * PADE];
            kc2 = kp[(long)(g + 10) * PADE];
            kc3 = kp[(long)(g + 11) * PADE];
        }
        PROC4(ka0, g + 0)
        PROC4(ka1, g + 1)
        PROC4(ka2, g + 2)
        PROC4(ka3, g + 3)
        ka0 = kb0; ka1 = kb1; ka2 = kb2; ka3 = kb3;
        kb0 = kc0; kb1 = kc1; kb2 = kc2; kb3 = kc3;
    }
#undef PROC4

    float val0 = -2.f * T0;
    float val1 = -2.f * T1;

    // ---- log-softmax over k, no max pass (|val| <= 2*sum|v| ~ 16, safe) ----
    __shared__ float red[8][2];
    const int lane = k & 63, wv = k >> 6;

    float e0 = __builtin_amdgcn_exp2f(val0 * 1.4426950408889634f);
    float e1 = __builtin_amdgcn_exp2f(val1 * 1.4426950408889634f);
    #pragma unroll
    for (int o = 32; o; o >>= 1) {
        e0 += __shfl_xor(e0, o, 64);
        e1 += __shfl_xor(e1, o, 64);
    }
    if (lane == 0) { red[wv][0] = e0; red[wv][1] = e1; }
    __syncthreads();
    float s0 = 0.f, s1 = 0.f;
    #pragma unroll
    for (int w = 0; w < 8; ++w) { s0 += red[w][0]; s1 += red[w][1]; }

    float l0 = __builtin_amdgcn_logf(s0) * 0.6931471805599453f;  // ln(s0)
    float l1 = __builtin_amdgcn_logf(s1) * 0.6931471805599453f;
    out[((long)b * NQ_ + q0 + 0) * NK_ + k] = val0 - l0;
    out[((long)b * NQ_ + q0 + 1) * NK_ + k] = val1 - l1;
}

extern "C" void kernel_launch(void* const* d_in, const int* in_sizes, int n_in,
                              void* d_out, int out_size, void* d_ws, size_t ws_size,
                              hipStream_t stream)
{
    const float* xq = (const float*)d_in[0];  // (4,256,256)
    const float* xk = (const float*)d_in[1];  // (4,512,256)
    const float* w1 = (const float*)d_in[2];  // (256,256) out,in
    const float* w2 = (const float*)d_in[3];  // (256,256)
    const float* v  = (const float*)d_in[4];  // (1,256)
    float* out = (float*)d_out;

    float* Ebuf = (float*)d_ws;                             // [4][64][516*4] ~2.1 MB
    float* Fbuf = Ebuf + (size_t)B_ * 64 * PADE * 4;        // [4][256][256]  = 1 MB

    gemm_fused<<<dim3(192), 256, 0, stream>>>(xq, xk, w1, w2, Ebuf, Fbuf);
    attn_main<<<dim3(NQ_ / 2, B_), 512, 0, stream>>>(
        (const float4*)Ebuf, Fbuf, v, out);
}